// Round 1
// baseline (176.170 us; speedup 1.0000x reference)
//
#include <hip/hip_runtime.h>
#include <hip/hip_cooperative_groups.h>

namespace cg = cooperative_groups;

// Problem: B=64, P=128, D=1024 (fp32)
//   s[b,p] = dot(concat(h,q)[b,p], W_att)   (b_att uniform -> cancels in softmax)
//   t[b,p] = dot(concat(h,q)[b,p], W_fc)
//   out[b] = sum_p softmax_P(s)[b,p] * t[b,p] + b_fc
//
// Single cooperative kernel:
//   Stage 1: 1024 blocks x 256 thr, 8 rows/block. Weight fragments hoisted to
//            registers (read once per block, not once per row) -> weight L2
//            traffic 134MB -> 17MB. h/q rows streamed once: 67MB HBM floor.
//   grid.sync()
//   Stage 2: blocks 0..63 do the P=128 softmax+pool for one batch each.

#define BB 64
#define PP 128
#define DD 1024
#define NBLK 1024   // 4 blocks/CU on 256 CUs -> cooperative co-residency exact
#define RPB 8       // rows per block: 1024*8 = 8192 = B*P

__global__ __launch_bounds__(256, 4) void fused_kernel(
    const float* __restrict__ h,
    const float* __restrict__ q,
    const float* __restrict__ Watt,
    const float* __restrict__ Wfc,
    const float* __restrict__ b_fc,
    float* __restrict__ s_ws,
    float* __restrict__ t_ws,
    float* __restrict__ out)
{
    const int  tid  = threadIdx.x;     // 0..255 (4 waves)
    const bool isq  = tid >= 128;      // lower half covers h, upper half covers q
    const int  j    = tid & 127;       // float4-chunk lane within the 1024-f half
    const int  wave = tid >> 6;
    const int  lane = tid & 63;

    // ---- Stage 1: dual dot products, 8 rows per block ----
    {
        // weight fragments: registers, loaded ONCE per block (16 VGPRs)
        const float4* wa4 = (const float4*)(Watt + (isq ? DD : 0));
        const float4* wf4 = (const float4*)(Wfc  + (isq ? DD : 0));
        const float4 wa0 = wa4[j], wa1 = wa4[j + 128];
        const float4 wf0 = wf4[j], wf1 = wf4[j + 128];

        const float* base = isq ? q : h;
        const int r0 = blockIdx.x * RPB;

        __shared__ float sh_s[RPB][4], sh_t[RPB][4];

        #pragma unroll
        for (int k = 0; k < RPB; ++k) {
            const float4* row4 = (const float4*)(base + (size_t)(r0 + k) * DD);
            const float4 x0 = row4[j];         // coalesced 16B/lane
            const float4 x1 = row4[j + 128];
            float s = x0.x*wa0.x + x0.y*wa0.y + x0.z*wa0.z + x0.w*wa0.w
                    + x1.x*wa1.x + x1.y*wa1.y + x1.z*wa1.z + x1.w*wa1.w;
            float t = x0.x*wf0.x + x0.y*wf0.y + x0.z*wf0.z + x0.w*wf0.w
                    + x1.x*wf1.x + x1.y*wf1.y + x1.z*wf1.z + x1.w*wf1.w;
            #pragma unroll
            for (int off = 32; off > 0; off >>= 1) {
                s += __shfl_down(s, off, 64);
                t += __shfl_down(t, off, 64);
            }
            if (lane == 0) { sh_s[k][wave] = s; sh_t[k][wave] = t; }
        }
        __syncthreads();
        if (tid < RPB) {
            const int r = blockIdx.x * RPB + tid;
            s_ws[r] = sh_s[tid][0] + sh_s[tid][1] + sh_s[tid][2] + sh_s[tid][3];
            t_ws[r] = sh_t[tid][0] + sh_t[tid][1] + sh_t[tid][2] + sh_t[tid][3];
        }
    }

    cg::this_grid().sync();

    // ---- Stage 2: softmax over P + weighted pool, blocks 0..63 ----
    if (blockIdx.x >= BB) return;
    const int b = blockIdx.x;

    float s = -INFINITY, t = 0.f;       // waves 2,3 carry neutral values
    if (tid < PP) { s = s_ws[b * PP + tid]; t = t_ws[b * PP + tid]; }

    float m = s;
    #pragma unroll
    for (int off = 32; off > 0; off >>= 1) m = fmaxf(m, __shfl_down(m, off, 64));
    __shared__ float sh_m[4], sh_z[4], sh_n[4];
    if (lane == 0) sh_m[wave] = m;
    __syncthreads();
    m = fmaxf(fmaxf(sh_m[0], sh_m[1]), fmaxf(sh_m[2], sh_m[3]));

    float e   = __expf(s - m);          // exp(-inf) = 0 for padding lanes
    float num = e * t;
    #pragma unroll
    for (int off = 32; off > 0; off >>= 1) {
        e   += __shfl_down(e, off, 64);
        num += __shfl_down(num, off, 64);
    }
    if (lane == 0) { sh_z[wave] = e; sh_n[wave] = num; }
    __syncthreads();
    if (tid == 0) {
        const float Z = sh_z[0] + sh_z[1] + sh_z[2] + sh_z[3];
        const float N = sh_n[0] + sh_n[1] + sh_n[2] + sh_n[3];
        out[b] = N / Z + b_fc[0];
    }
}

extern "C" void kernel_launch(void* const* d_in, const int* in_sizes, int n_in,
                              void* d_out, int out_size, void* d_ws, size_t ws_size,
                              hipStream_t stream) {
    const float* h     = (const float*)d_in[0];
    const float* q     = (const float*)d_in[1];
    const float* W_att = (const float*)d_in[2];
    // d_in[3] = b_att (uniform -> cancels in softmax)
    const float* W_fc  = (const float*)d_in[4];
    const float* b_fc  = (const float*)d_in[5];

    float* s_ws = (float*)d_ws;                 // B*P floats
    float* t_ws = s_ws + BB * PP;               // B*P floats
    float* outp = (float*)d_out;

    void* args[] = {(void*)&h, (void*)&q, (void*)&W_att, (void*)&W_fc,
                    (void*)&b_fc, (void*)&s_ws, (void*)&t_ws, (void*)&outp};
    hipLaunchCooperativeKernel((const void*)fused_kernel,
                               dim3(NBLK), dim3(256), args, 0, stream);
}

// Round 2
// 101.876 us; speedup vs baseline: 1.7293x; 1.7293x over previous
//
#include <hip/hip_runtime.h>

// Problem: B=64, P=128, D=1024 (fp32)
//   s[b,p] = dot(concat(h,q)[b,p], W_att)   (b_att uniform -> cancels in softmax)
//   t[b,p] = dot(concat(h,q)[b,p], W_fc)
//   out[b] = sum_p softmax_P(s)[b,p] * t[b,p] + b_fc
//
// Two dispatches (cooperative grid.sync measured at ~85us on this part -- do
// NOT fuse via cg). Controllable floor: 67MB h+q read ~11us + ~2us stage 2.

#define BB 64
#define PP 128
#define DD 1024
#define RPB 4   // rows per block in stage 1

// Stage 1: 2048 blocks x 256 thr; each block does 4 consecutive (b,p) rows.
// Threads 0..127 cover the h-half, 128..255 the q-half; each thread owns the
// same 8 columns (2 float4) of its half for all 4 rows, so the weight
// fragments live in registers and are loaded once per block (4x less weight
// traffic than one-row-per-block). 8 row float4 loads issued back-to-back per
// thread -> deep VMEM pipeline, fully coalesced 16B/lane.
__global__ __launch_bounds__(256) void score_kernel(
    const float* __restrict__ h,
    const float* __restrict__ q,
    const float* __restrict__ Watt,
    const float* __restrict__ Wfc,
    float* __restrict__ s_out, float* __restrict__ t_out)
{
    const int  tid  = threadIdx.x;     // 0..255
    const bool isq  = tid >= 128;
    const int  j    = tid & 127;       // float4-chunk lane within the half
    const int  wave = tid >> 6;
    const int  lane = tid & 63;
    const int  r0   = blockIdx.x * RPB;

    // weight fragments: 16 VGPRs, loaded once per block (L2/L1 hits)
    const float4* wa4 = (const float4*)(Watt + (isq ? DD : 0));
    const float4* wf4 = (const float4*)(Wfc  + (isq ? DD : 0));
    const float4 wa0 = wa4[j], wa1 = wa4[j + 128];
    const float4 wf0 = wf4[j], wf1 = wf4[j + 128];

    const float* base = (isq ? q : h) + (size_t)r0 * DD;

    // issue all 8 row loads first (static indices -> registers, rule #20)
    float4 x0[RPB], x1[RPB];
    #pragma unroll
    for (int k = 0; k < RPB; ++k) {
        const float4* row4 = (const float4*)(base + (size_t)k * DD);
        x0[k] = row4[j];
        x1[k] = row4[j + 128];
    }

    __shared__ float sh_s[RPB][4], sh_t[RPB][4];
    #pragma unroll
    for (int k = 0; k < RPB; ++k) {
        float s = x0[k].x*wa0.x + x0[k].y*wa0.y + x0[k].z*wa0.z + x0[k].w*wa0.w
                + x1[k].x*wa1.x + x1[k].y*wa1.y + x1[k].z*wa1.z + x1[k].w*wa1.w;
        float t = x0[k].x*wf0.x + x0[k].y*wf0.y + x0[k].z*wf0.z + x0[k].w*wf0.w
                + x1[k].x*wf1.x + x1[k].y*wf1.y + x1[k].z*wf1.z + x1[k].w*wf1.w;
        #pragma unroll
        for (int off = 32; off > 0; off >>= 1) {   // independent chain per row
            s += __shfl_down(s, off, 64);
            t += __shfl_down(t, off, 64);
        }
        if (lane == 0) { sh_s[k][wave] = s; sh_t[k][wave] = t; }
    }
    __syncthreads();
    if (tid < RPB) {
        const int r = r0 + tid;
        s_out[r] = sh_s[tid][0] + sh_s[tid][1] + sh_s[tid][2] + sh_s[tid][3];
        t_out[r] = sh_t[tid][0] + sh_t[tid][1] + sh_t[tid][2] + sh_t[tid][3];
    }
}

// Stage 2: one wave per batch; softmax over P=128 + weighted pool.
// No LDS, no __syncthreads: each lane holds 2 of the 128 scores.
__global__ __launch_bounds__(64) void softmax_pool_kernel(
    const float* __restrict__ s_in, const float* __restrict__ t_in,
    const float* __restrict__ b_fc,
    float* __restrict__ out)
{
    const int b = blockIdx.x;
    const int l = threadIdx.x;          // 0..63, one wave
    const float s0 = s_in[b * PP + l];
    const float s1 = s_in[b * PP + 64 + l];
    const float t0 = t_in[b * PP + l];
    const float t1 = t_in[b * PP + 64 + l];

    float m = fmaxf(s0, s1);
    #pragma unroll
    for (int off = 32; off > 0; off >>= 1) m = fmaxf(m, __shfl_down(m, off, 64));
    m = __shfl(m, 0, 64);               // broadcast wave max

    const float e0 = __expf(s0 - m), e1 = __expf(s1 - m);
    float z = e0 + e1;
    float n = e0 * t0 + e1 * t1;
    #pragma unroll
    for (int off = 32; off > 0; off >>= 1) {
        z += __shfl_down(z, off, 64);
        n += __shfl_down(n, off, 64);
    }
    if (l == 0) out[b] = n / z + b_fc[0];
}

extern "C" void kernel_launch(void* const* d_in, const int* in_sizes, int n_in,
                              void* d_out, int out_size, void* d_ws, size_t ws_size,
                              hipStream_t stream) {
    const float* h     = (const float*)d_in[0];
    const float* q     = (const float*)d_in[1];
    const float* W_att = (const float*)d_in[2];
    // d_in[3] = b_att (uniform -> cancels in softmax)
    const float* W_fc  = (const float*)d_in[4];
    const float* b_fc  = (const float*)d_in[5];

    float* s_ws = (float*)d_ws;                 // B*P floats
    float* t_ws = s_ws + BB * PP;               // B*P floats

    score_kernel<<<(BB * PP) / RPB, 256, 0, stream>>>(h, q, W_att, W_fc, s_ws, t_ws);
    softmax_pool_kernel<<<BB, 64, 0, stream>>>(s_ws, t_ws, b_fc, (float*)d_out);
}

// Round 3
// 99.733 us; speedup vs baseline: 1.7664x; 1.0215x over previous
//
#include <hip/hip_runtime.h>

// Problem: B=64, P=128, D=1024 (fp32)
//   s[b,p] = dot(concat(h,q)[b,p], W_att)   (b_att uniform -> cancels in softmax)
//   t[b,p] = dot(concat(h,q)[b,p], W_fc)
//   out[b] = sum_p softmax_P(s)[b,p] * t[b,p] + b_fc
//
// Structure notes from this session (keep!):
//  - Timed region is ~83% harness poison fills (2x268MB @ ~81% HBM peak).
//    Controllable slice ~13-17us vs ~12us floor (67MB mandatory h+q read).
//  - cg grid.sync costs ~85us on gfx950 at 1024 blocks -- never fuse via cg.
//  - Row-batching (RPB=4, weights hoisted) REGRESSED 2.2us: weights are
//    L1-resident anyway; the simple 1-row/block shape is measured-best.

#define BB 64
#define PP 128
#define DD 1024

// Stage 1: one block (256 thr) per (b,p) row; both dots in fp32.
// t<128 covers h-half, t>=128 covers q-half; each thread reads 2 float4
// chunks (8 floats) of its 1024-float half -> fully coalesced 16B/lane.
__global__ __launch_bounds__(256) void score_kernel(
    const float* __restrict__ h,
    const float* __restrict__ q,
    const float* __restrict__ Watt,
    const float* __restrict__ Wfc,
    float* __restrict__ s_out, float* __restrict__ t_out)
{
    const int r   = blockIdx.x;        // b*PP + p
    const int tid = threadIdx.x;       // 0..255
    const bool isq = tid >= 128;
    const int j = tid & 127;           // float4-chunk lane within half

    const float* row = (isq ? q : h) + (size_t)r * DD;
    const float* wa  = Watt + (isq ? DD : 0);
    const float* wf  = Wfc  + (isq ? DD : 0);

    const float4* row4 = (const float4*)row;
    const float4* wa4  = (const float4*)wa;   // L1-resident after 1st block/CU
    const float4* wf4  = (const float4*)wf;

    float s_acc = 0.f, t_acc = 0.f;
    #pragma unroll
    for (int c = 0; c < 2; ++c) {
        const int idx = j + c * 128;   // 256 float4 chunks per 1024-float half
        float4 x = row4[idx];
        float4 a = wa4[idx];
        float4 f = wf4[idx];
        s_acc += x.x*a.x + x.y*a.y + x.z*a.z + x.w*a.w;
        t_acc += x.x*f.x + x.y*f.y + x.z*f.z + x.w*f.w;
    }

    // wave(64) shuffle reduce, both accumulators
    #pragma unroll
    for (int off = 32; off > 0; off >>= 1) {
        s_acc += __shfl_down(s_acc, off, 64);
        t_acc += __shfl_down(t_acc, off, 64);
    }

    __shared__ float sh_s[4], sh_t[4];
    const int wave = tid >> 6;
    if ((tid & 63) == 0) { sh_s[wave] = s_acc; sh_t[wave] = t_acc; }
    __syncthreads();
    if (tid == 0) {
        s_out[r] = sh_s[0] + sh_s[1] + sh_s[2] + sh_s[3];
        t_out[r] = sh_t[0] + sh_t[1] + sh_t[2] + sh_t[3];
    }
}

// Stage 2: one wave per batch; softmax over P=128 + weighted pool.
// No LDS, no __syncthreads: each lane holds 2 of the 128 scores.
__global__ __launch_bounds__(64) void softmax_pool_kernel(
    const float* __restrict__ s_in, const float* __restrict__ t_in,
    const float* __restrict__ b_fc,
    float* __restrict__ out)
{
    const int b = blockIdx.x;
    const int l = threadIdx.x;          // 0..63, one wave
    const float s0 = s_in[b * PP + l];
    const float s1 = s_in[b * PP + 64 + l];
    const float t0 = t_in[b * PP + l];
    const float t1 = t_in[b * PP + 64 + l];

    float m = fmaxf(s0, s1);
    #pragma unroll
    for (int off = 32; off > 0; off >>= 1) m = fmaxf(m, __shfl_down(m, off, 64));
    m = __shfl(m, 0, 64);               // broadcast wave max

    const float e0 = __expf(s0 - m), e1 = __expf(s1 - m);
    float z = e0 + e1;
    float n = e0 * t0 + e1 * t1;
    #pragma unroll
    for (int off = 32; off > 0; off >>= 1) {
        z += __shfl_down(z, off, 64);
        n += __shfl_down(n, off, 64);
    }
    if (l == 0) out[b] = n / z + b_fc[0];
}

extern "C" void kernel_launch(void* const* d_in, const int* in_sizes, int n_in,
                              void* d_out, int out_size, void* d_ws, size_t ws_size,
                              hipStream_t stream) {
    const float* h     = (const float*)d_in[0];
    const float* q     = (const float*)d_in[1];
    const float* W_att = (const float*)d_in[2];
    // d_in[3] = b_att (uniform -> cancels in softmax)
    const float* W_fc  = (const float*)d_in[4];
    const float* b_fc  = (const float*)d_in[5];

    float* s_ws = (float*)d_ws;                 // B*P floats
    float* t_ws = s_ws + BB * PP;               // B*P floats

    score_kernel<<<BB * PP, 256, 0, stream>>>(h, q, W_att, W_fc, s_ws, t_ws);
    softmax_pool_kernel<<<BB, 64, 0, stream>>>(s_ws, t_ws, b_fc, (float*)d_out);
}